// Round 1
// baseline (647.520 us; speedup 1.0000x reference)
//
#include <hip/hip_runtime.h>

typedef __bf16 bf16_t;
typedef bf16_t bf16x4 __attribute__((ext_vector_type(4)));
typedef bf16_t bf16x8 __attribute__((ext_vector_type(8)));
typedef float floatx4 __attribute__((ext_vector_type(4)));

#define EPSF 1e-5f
#define DEV static __device__ __forceinline__

// ---------------------------------------------------------------------------
// K0: swizzle weight matrices (f32 [K][128]) into B-fragment order, bf16.
// sw[((t*nK + s)*64 + l)*8 + j] = W[(s*32 + (l>>4)*8 + j)*128 + (t*16 + (l&15))]
// Layout ranges (bf16 elems): W_in@0(16384), W_ctx1@16384(32768),
// W_ctx2@49152(16384), W_m1@65536(16384), W_m2@81920(16384). Total 98304.
// ---------------------------------------------------------------------------
__global__ __launch_bounds__(256) void k_prep(
    const float* __restrict__ W_in, const float* __restrict__ W_ctx1,
    const float* __restrict__ W_ctx2, const float* __restrict__ W_m1,
    const float* __restrict__ W_m2, bf16_t* __restrict__ sw)
{
    int idx = blockIdx.x * 256 + threadIdx.x;   // grid sized to exactly 98304
    const float* W; int base, ks;
    if (idx < 16384)      { W = W_in;   base = 0;     ks = 2; }
    else if (idx < 49152) { W = W_ctx1; base = 16384; ks = 3; }
    else if (idx < 65536) { W = W_ctx2; base = 49152; ks = 2; }
    else if (idx < 81920) { W = W_m1;   base = 65536; ks = 2; }
    else                  { W = W_m2;   base = 81920; ks = 2; }
    int local = idx - base;
    int j = local & 7, l = (local >> 3) & 63, rest = local >> 9;
    int s = rest & ((1 << ks) - 1), t = rest >> ks;
    int k = s * 32 + (l >> 4) * 8 + j;
    int n = t * 16 + (l & 15);
    sw[idx] = (bf16_t)W[k * 128 + n];
}

// GroupNorm over 128 channels per row, operating on MFMA C-layout accumulators.
// acc[t][rr] holds element (row = (lane>>4)*4+rr, col = t*16 + (lane&15)).
DEV void gn_rows(floatx4* acc, int lane, const float* __restrict__ gamma,
                 const float* __restrict__ beta, bool do_relu)
{
    int m = lane & 15;
    float s1[4] = {0.f,0.f,0.f,0.f}, s2[4] = {0.f,0.f,0.f,0.f};
#pragma unroll
    for (int t = 0; t < 8; ++t)
#pragma unroll
        for (int rr = 0; rr < 4; ++rr) { float v = acc[t][rr]; s1[rr] += v; s2[rr] += v*v; }
#pragma unroll
    for (int mask = 1; mask <= 8; mask <<= 1)
#pragma unroll
        for (int rr = 0; rr < 4; ++rr) {
            s1[rr] += __shfl_xor(s1[rr], mask);
            s2[rr] += __shfl_xor(s2[rr], mask);
        }
    float mean[4], inv[4];
#pragma unroll
    for (int rr = 0; rr < 4; ++rr) {
        mean[rr] = s1[rr] * (1.f/128.f);
        float var = s2[rr] * (1.f/128.f) - mean[rr]*mean[rr];
        inv[rr] = rsqrtf(var + EPSF);
    }
#pragma unroll
    for (int t = 0; t < 8; ++t) {
        int n = t*16 + m;
        float ga = gamma[n], be = beta[n];
#pragma unroll
        for (int rr = 0; rr < 4; ++rr) {
            float v = (acc[t][rr] - mean[rr]) * inv[rr] * ga + be;
            acc[t][rr] = do_relu ? fmaxf(v, 0.f) : v;
        }
    }
}

// ---------------------------------------------------------------------------
// K1: tf = target_feat @ W_in   (f32 out into workspace)
// ---------------------------------------------------------------------------
__global__ __launch_bounds__(256) void k_gemm_in(
    const float* __restrict__ tfeat, const bf16_t* __restrict__ swW,
    float* __restrict__ tf, int Nt)
{
    __shared__ alignas(16) bf16_t sB[16384];      // W_in swizzled, 32 KB
    __shared__ alignas(16) bf16_t sA[4][2048];    // per-wave A tile (A-frag order)
    int tid = threadIdx.x, lane = tid & 63, wave = tid >> 6;
#pragma unroll
    for (int i = 0; i < 8; ++i)
        ((uint4*)sB)[tid + i*256] = ((const uint4*)swW)[tid + i*256];

    int tb = (blockIdx.x * 4 + wave) * 16;
    int r = lane >> 2, cb = (lane & 3) * 32;
    int grow = tb + r;
    bool rv = grow < Nt;
    const float4* src = (const float4*)(tfeat + (size_t)(rv ? grow : 0) * 128 + cb);
#pragma unroll
    for (int i = 0; i < 8; ++i) {
        float4 v = rv ? src[i] : make_float4(0.f,0.f,0.f,0.f);
        int k = cb + 4*i;
        int s = k >> 5, q = (k >> 3) & 3, j = k & 7;
        bf16x4 pk = { (bf16_t)v.x, (bf16_t)v.y, (bf16_t)v.z, (bf16_t)v.w };
        *(bf16x4*)&sA[wave][(s*64 + q*16 + r)*8 + j] = pk;
    }
    __syncthreads();
    int m = lane & 15, g = lane >> 4;
    bf16x8 aF[4];
#pragma unroll
    for (int s = 0; s < 4; ++s) aF[s] = *(const bf16x8*)&sA[wave][(s*64 + lane)*8];
#pragma unroll
    for (int t = 0; t < 8; ++t) {
        floatx4 a = {0.f,0.f,0.f,0.f};
#pragma unroll
        for (int s = 0; s < 4; ++s) {
            bf16x8 bF = *(const bf16x8*)&sB[((t*4+s)*64 + lane)*8];
            a = __builtin_amdgcn_mfma_f32_16x16x32_bf16(aF[s], bF, a, 0, 0, 0);
        }
#pragma unroll
        for (int rr = 0; rr < 4; ++rr) {
            int row = tb + g*4 + rr;
            if (row < Nt) tf[(size_t)row*128 + t*16 + m] = a[rr];
        }
    }
}

// ---------------------------------------------------------------------------
// K2: per-edge MLP + scatter-add.
// ---------------------------------------------------------------------------
__global__ __launch_bounds__(256) void k_edge(
    const float* __restrict__ cfeat, const float* __restrict__ cpose,
    const float* __restrict__ tpose, const int* __restrict__ hi,
    const int* __restrict__ wi, const float* __restrict__ W_rp,
    const float* __restrict__ b_rp, const float* __restrict__ g_ctx,
    const float* __restrict__ be_ctx, const bf16_t* __restrict__ swC1,
    const bf16_t* __restrict__ swC2, float* __restrict__ tf, int E)
{
    __shared__ alignas(16) bf16_t sB2[16384];     // W_ctx2 swizzled, 32 KB
    __shared__ alignas(16) bf16_t sA[4][4096];    // per-wave [16 x 256] A-frag order
    int tid = threadIdx.x, lane = tid & 63, wave = tid >> 6;
#pragma unroll
    for (int i = 0; i < 8; ++i)
        ((uint4*)sB2)[tid + i*256] = ((const uint4*)swC2)[tid + i*256];

    int tb = (blockIdx.x * 4 + wave) * 16;
    int r = lane >> 2, cb = (lane & 3) * 32;
    int e = min(tb + r, E - 1);
    int ci = hi[e], ti = wi[e];
    // context features -> k in [0,128)
    const float4* src = (const float4*)(cfeat + (size_t)ci * 128 + cb);
#pragma unroll
    for (int i = 0; i < 8; ++i) {
        float4 v = src[i];
        int k = cb + 4*i;
        int s = k >> 5, q = (k >> 3) & 3, j = k & 7;
        bf16x4 pk = { (bf16_t)v.x, (bf16_t)v.y, (bf16_t)v.z, (bf16_t)v.w };
        *(bf16x4*)&sA[wave][(s*64 + q*16 + r)*8 + j] = pk;
    }
    // relpose MLP -> k in [128,256)
    float4 cp = ((const float4*)cpose)[ci];
    float4 tp = ((const float4*)tpose)[ti];
    float d0 = cp.x - tp.x, d1 = cp.y - tp.y, d2 = cp.z - tp.z, d3 = cp.w - tp.w;
#pragma unroll
    for (int i = 0; i < 8; ++i) {
        int c = cb + 4*i;
        float4 w0 = *(const float4*)(W_rp + c);
        float4 w1 = *(const float4*)(W_rp + 128 + c);
        float4 w2 = *(const float4*)(W_rp + 256 + c);
        float4 w3 = *(const float4*)(W_rp + 384 + c);
        float4 bb = *(const float4*)(b_rp + c);
        float o0 = fmaxf(d0*w0.x + d1*w1.x + d2*w2.x + d3*w3.x + bb.x, 0.f);
        float o1 = fmaxf(d0*w0.y + d1*w1.y + d2*w2.y + d3*w3.y + bb.y, 0.f);
        float o2 = fmaxf(d0*w0.z + d1*w1.z + d2*w2.z + d3*w3.z + bb.z, 0.f);
        float o3 = fmaxf(d0*w0.w + d1*w1.w + d2*w2.w + d3*w3.w + bb.w, 0.f);
        int k = 128 + c;
        int s = k >> 5, q = (k >> 3) & 3, j = k & 7;
        bf16x4 pk = { (bf16_t)o0, (bf16_t)o1, (bf16_t)o2, (bf16_t)o3 };
        *(bf16x4*)&sA[wave][(s*64 + q*16 + r)*8 + j] = pk;
    }
    __syncthreads();

    int m = lane & 15, g = lane >> 4;
    bf16x8 aF[8];
#pragma unroll
    for (int s = 0; s < 8; ++s) aF[s] = *(const bf16x8*)&sA[wave][(s*64 + lane)*8];
    floatx4 acc[8];
#pragma unroll
    for (int t = 0; t < 8; ++t) {
        floatx4 a = {0.f,0.f,0.f,0.f};
#pragma unroll
        for (int s = 0; s < 8; ++s) {
            bf16x8 bF = *(const bf16x8*)&swC1[(size_t)((t*8+s)*64 + lane)*8];
            a = __builtin_amdgcn_mfma_f32_16x16x32_bf16(aF[s], bF, a, 0, 0, 0);
        }
        acc[t] = a;
    }
    gn_rows(acc, lane, g_ctx, be_ctx, true);
    __syncthreads();
    // write h back into sA (A-frag order, K=128 region)
#pragma unroll
    for (int t = 0; t < 8; ++t) {
        int n = t*16 + m;
        int s = n >> 5, q = (n >> 3) & 3, j = n & 7;
#pragma unroll
        for (int rr = 0; rr < 4; ++rr)
            sA[wave][(s*64 + q*16 + (g*4+rr))*8 + j] = (bf16_t)acc[t][rr];
    }
    __syncthreads();
    bf16x8 aF2[4];
#pragma unroll
    for (int s = 0; s < 4; ++s) aF2[s] = *(const bf16x8*)&sA[wave][(s*64 + lane)*8];
    int dstrow[4]; bool vald[4];
#pragma unroll
    for (int rr = 0; rr < 4; ++rr) {
        int ee = tb + g*4 + rr;
        vald[rr] = ee < E;
        dstrow[rr] = vald[rr] ? wi[ee] : 0;
    }
#pragma unroll
    for (int t = 0; t < 8; ++t) {
        floatx4 a = {0.f,0.f,0.f,0.f};
#pragma unroll
        for (int s = 0; s < 4; ++s) {
            bf16x8 bF = *(const bf16x8*)&sB2[((t*4+s)*64 + lane)*8];
            a = __builtin_amdgcn_mfma_f32_16x16x32_bf16(aF2[s], bF, a, 0, 0, 0);
        }
#pragma unroll
        for (int rr = 0; rr < 4; ++rr) {
            if (vald[rr])
                atomicAdd(&tf[(size_t)dstrow[rr]*128 + t*16 + m], a[rr]);
        }
    }
}

// ---------------------------------------------------------------------------
// K3: out = relu(GN(relu(GN(relu(GN(tf)) @ W_m1)) @ W_m2) + identity)
// ---------------------------------------------------------------------------
__global__ __launch_bounds__(256) void k_out(
    const float* __restrict__ tf, const float* __restrict__ identity,
    const float* __restrict__ g_n, const float* __restrict__ be_n,
    const float* __restrict__ g_m1, const float* __restrict__ be_m1,
    const float* __restrict__ g_m2, const float* __restrict__ be_m2,
    const bf16_t* __restrict__ swM1, const bf16_t* __restrict__ swM2,
    float* __restrict__ out, int Nt)
{
    __shared__ alignas(16) bf16_t sB[16384];      // W_m1 swizzled
    __shared__ alignas(16) bf16_t sA[4][2048];
    int tid = threadIdx.x, lane = tid & 63, wave = tid >> 6;
#pragma unroll
    for (int i = 0; i < 8; ++i)
        ((uint4*)sB)[tid + i*256] = ((const uint4*)swM1)[tid + i*256];

    int tb = (blockIdx.x*4 + wave)*16;
    int r = lane >> 2, cb = (lane & 3)*32;
    int grow = tb + r;
    bool rv = grow < Nt;
    const float4* src = (const float4*)(tf + (size_t)(rv ? grow : 0)*128 + cb);
    float vals[32];
    float ls = 0.f, lq = 0.f;
#pragma unroll
    for (int i = 0; i < 8; ++i) {
        float4 v = rv ? src[i] : make_float4(0.f,0.f,0.f,0.f);
        vals[4*i+0]=v.x; vals[4*i+1]=v.y; vals[4*i+2]=v.z; vals[4*i+3]=v.w;
        ls += v.x+v.y+v.z+v.w;
        lq += v.x*v.x+v.y*v.y+v.z*v.z+v.w*v.w;
    }
    ls += __shfl_xor(ls,1); lq += __shfl_xor(lq,1);
    ls += __shfl_xor(ls,2); lq += __shfl_xor(lq,2);
    float mean = ls*(1.f/128.f);
    float inv = rsqrtf(lq*(1.f/128.f) - mean*mean + EPSF);
#pragma unroll
    for (int i = 0; i < 8; ++i) {
        int c = cb + 4*i;
        float4 ga = *(const float4*)(g_n + c);
        float4 be = *(const float4*)(be_n + c);
        float o0 = fmaxf((vals[4*i+0]-mean)*inv*ga.x + be.x, 0.f);
        float o1 = fmaxf((vals[4*i+1]-mean)*inv*ga.y + be.y, 0.f);
        float o2 = fmaxf((vals[4*i+2]-mean)*inv*ga.z + be.z, 0.f);
        float o3 = fmaxf((vals[4*i+3]-mean)*inv*ga.w + be.w, 0.f);
        int s = c >> 5, q = (c >> 3) & 3, j = c & 7;
        bf16x4 pk = { (bf16_t)o0, (bf16_t)o1, (bf16_t)o2, (bf16_t)o3 };
        *(bf16x4*)&sA[wave][(s*64 + q*16 + r)*8 + j] = pk;
    }
    __syncthreads();
    int m = lane & 15, g = lane >> 4;
    bf16x8 aF[4];
#pragma unroll
    for (int s = 0; s < 4; ++s) aF[s] = *(const bf16x8*)&sA[wave][(s*64 + lane)*8];
    floatx4 acc[8];
#pragma unroll
    for (int t = 0; t < 8; ++t) {
        floatx4 a = {0.f,0.f,0.f,0.f};
#pragma unroll
        for (int s = 0; s < 4; ++s) {
            bf16x8 bF = *(const bf16x8*)&sB[((t*4+s)*64 + lane)*8];
            a = __builtin_amdgcn_mfma_f32_16x16x32_bf16(aF[s], bF, a, 0, 0, 0);
        }
        acc[t] = a;
    }
    gn_rows(acc, lane, g_m1, be_m1, true);
    __syncthreads();
#pragma unroll
    for (int t = 0; t < 8; ++t) {
        int n = t*16 + m;
        int s = n >> 5, q = (n >> 3) & 3, j = n & 7;
#pragma unroll
        for (int rr = 0; rr < 4; ++rr)
            sA[wave][(s*64 + q*16 + (g*4+rr))*8 + j] = (bf16_t)acc[t][rr];
    }
    __syncthreads();
#pragma unroll
    for (int s = 0; s < 4; ++s) aF[s] = *(const bf16x8*)&sA[wave][(s*64 + lane)*8];
#pragma unroll
    for (int t = 0; t < 8; ++t) {
        floatx4 a = {0.f,0.f,0.f,0.f};
#pragma unroll
        for (int s = 0; s < 4; ++s) {
            bf16x8 bF = *(const bf16x8*)&swM2[((t*4+s)*64 + lane)*8];
            a = __builtin_amdgcn_mfma_f32_16x16x32_bf16(aF[s], bF, a, 0, 0, 0);
        }
        acc[t] = a;
    }
    gn_rows(acc, lane, g_m2, be_m2, false);
#pragma unroll
    for (int t = 0; t < 8; ++t) {
        int n = t*16 + m;
#pragma unroll
        for (int rr = 0; rr < 4; ++rr) {
            int row = tb + g*4 + rr;
            if (row < Nt) {
                float v = acc[t][rr] + identity[(size_t)row*128 + n];
                out[(size_t)row*128 + n] = fmaxf(v, 0.f);
            }
        }
    }
}

// ---------------------------------------------------------------------------
extern "C" void kernel_launch(void* const* d_in, const int* in_sizes, int n_in,
                              void* d_out, int out_size, void* d_ws, size_t ws_size,
                              hipStream_t stream)
{
    const float* cfeat  = (const float*)d_in[0];
    const float* tfeat  = (const float*)d_in[1];
    const float* cpose  = (const float*)d_in[2];
    const float* tpose  = (const float*)d_in[3];
    const int*   hi     = (const int*)d_in[4];
    const int*   wi     = (const int*)d_in[5];
    const float* W_in   = (const float*)d_in[6];
    const float* W_rp   = (const float*)d_in[7];
    const float* b_rp   = (const float*)d_in[8];
    const float* W_ctx1 = (const float*)d_in[9];
    const float* g_ctx  = (const float*)d_in[10];
    const float* be_ctx = (const float*)d_in[11];
    const float* W_ctx2 = (const float*)d_in[12];
    const float* g_n    = (const float*)d_in[13];
    const float* be_n   = (const float*)d_in[14];
    const float* W_m1   = (const float*)d_in[15];
    const float* g_m1   = (const float*)d_in[16];
    const float* be_m1  = (const float*)d_in[17];
    const float* W_m2   = (const float*)d_in[18];
    const float* g_m2   = (const float*)d_in[19];
    const float* be_m2  = (const float*)d_in[20];

    int Nt = in_sizes[1] / 128;
    int E  = in_sizes[4];
    float* outp = (float*)d_out;

    float*  tf = (float*)d_ws;                                   // [Nt,128] f32
    bf16_t* sw = (bf16_t*)((char*)d_ws + (size_t)Nt * 128 * sizeof(float));
    bf16_t* swIn = sw;
    bf16_t* swC1 = sw + 16384;
    bf16_t* swC2 = sw + 49152;
    bf16_t* swM1 = sw + 65536;
    bf16_t* swM2 = sw + 81920;

    k_prep<<<384, 256, 0, stream>>>(W_in, W_ctx1, W_ctx2, W_m1, W_m2, sw);
    k_gemm_in<<<(Nt + 63) / 64, 256, 0, stream>>>(tfeat, swIn, tf, Nt);
    k_edge<<<(E + 63) / 64, 256, 0, stream>>>(cfeat, cpose, tpose, hi, wi,
                                              W_rp, b_rp, g_ctx, be_ctx,
                                              swC1, swC2, tf, E);
    k_out<<<(Nt + 63) / 64, 256, 0, stream>>>(tf, tfeat, g_n, be_n, g_m1, be_m1,
                                              g_m2, be_m2, swM1, swM2, outp, Nt);
}

// Round 2
// 637.244 us; speedup vs baseline: 1.0161x; 1.0161x over previous
//
#include <hip/hip_runtime.h>

typedef __bf16 bf16_t;
typedef bf16_t bf16x4 __attribute__((ext_vector_type(4)));
typedef bf16_t bf16x8 __attribute__((ext_vector_type(8)));
typedef float floatx4 __attribute__((ext_vector_type(4)));

#define EPSF 1e-5f
#define DEV static __device__ __forceinline__

// ---------------------------------------------------------------------------
// K0: swizzle weight matrices (f32 [K][128]) into B-fragment order, bf16.
// sw[((t*nK + s)*64 + l)*8 + j] = W[(s*32 + (l>>4)*8 + j)*128 + (t*16 + (l&15))]
// Layout ranges (bf16 elems): W_in@0(16384), W_ctx1@16384(32768),
// W_ctx2@49152(16384), W_m1@65536(16384), W_m2@81920(16384). Total 98304.
// ---------------------------------------------------------------------------
__global__ __launch_bounds__(256) void k_prep(
    const float* __restrict__ W_in, const float* __restrict__ W_ctx1,
    const float* __restrict__ W_ctx2, const float* __restrict__ W_m1,
    const float* __restrict__ W_m2, bf16_t* __restrict__ sw)
{
    int idx = blockIdx.x * 256 + threadIdx.x;   // grid sized to exactly 98304
    const float* W; int base, ks;
    if (idx < 16384)      { W = W_in;   base = 0;     ks = 2; }
    else if (idx < 49152) { W = W_ctx1; base = 16384; ks = 3; }
    else if (idx < 65536) { W = W_ctx2; base = 49152; ks = 2; }
    else if (idx < 81920) { W = W_m1;   base = 65536; ks = 2; }
    else                  { W = W_m2;   base = 81920; ks = 2; }
    int local = idx - base;
    int j = local & 7, l = (local >> 3) & 63, rest = local >> 9;
    int s = rest & ((1 << ks) - 1), t = rest >> ks;
    int k = s * 32 + (l >> 4) * 8 + j;
    int n = t * 16 + (l & 15);
    sw[idx] = (bf16_t)W[k * 128 + n];
}

// GroupNorm over 128 channels per row, operating on MFMA C-layout accumulators.
// acc[t][rr] holds element (row = (lane>>4)*4+rr, col = t*16 + (lane&15)).
DEV void gn_rows(floatx4* acc, int lane, const float* __restrict__ gamma,
                 const float* __restrict__ beta, bool do_relu)
{
    int m = lane & 15;
    float s1[4] = {0.f,0.f,0.f,0.f}, s2[4] = {0.f,0.f,0.f,0.f};
#pragma unroll
    for (int t = 0; t < 8; ++t)
#pragma unroll
        for (int rr = 0; rr < 4; ++rr) { float v = acc[t][rr]; s1[rr] += v; s2[rr] += v*v; }
#pragma unroll
    for (int mask = 1; mask <= 8; mask <<= 1)
#pragma unroll
        for (int rr = 0; rr < 4; ++rr) {
            s1[rr] += __shfl_xor(s1[rr], mask);
            s2[rr] += __shfl_xor(s2[rr], mask);
        }
    float mean[4], inv[4];
#pragma unroll
    for (int rr = 0; rr < 4; ++rr) {
        mean[rr] = s1[rr] * (1.f/128.f);
        float var = s2[rr] * (1.f/128.f) - mean[rr]*mean[rr];
        inv[rr] = rsqrtf(var + EPSF);
    }
#pragma unroll
    for (int t = 0; t < 8; ++t) {
        int n = t*16 + m;
        float ga = gamma[n], be = beta[n];
#pragma unroll
        for (int rr = 0; rr < 4; ++rr) {
            float v = (acc[t][rr] - mean[rr]) * inv[rr] * ga + be;
            acc[t][rr] = do_relu ? fmaxf(v, 0.f) : v;
        }
    }
}

// ---------------------------------------------------------------------------
// K1: tf = target_feat @ W_in   (f32 out into workspace)
// B streamed from L2 (swizzled weights are 32 KB, hot). LDS = 16 KB/block.
// ---------------------------------------------------------------------------
__global__ __launch_bounds__(256) void k_gemm_in(
    const float* __restrict__ tfeat, const bf16_t* __restrict__ swW,
    float* __restrict__ tf, int Nt)
{
    __shared__ alignas(16) bf16_t sA[4][2048];    // per-wave A tile (A-frag order)
    int tid = threadIdx.x, lane = tid & 63, wave = tid >> 6;

    int tb = (blockIdx.x * 4 + wave) * 16;
    int r = lane >> 2, cb = (lane & 3) * 32;
    int grow = tb + r;
    bool rv = grow < Nt;
    const float4* src = (const float4*)(tfeat + (size_t)(rv ? grow : 0) * 128 + cb);
#pragma unroll
    for (int i = 0; i < 8; ++i) {
        float4 v = rv ? src[i] : make_float4(0.f,0.f,0.f,0.f);
        int k = cb + 4*i;
        int s = k >> 5, q = (k >> 3) & 3, j = k & 7;
        bf16x4 pk = { (bf16_t)v.x, (bf16_t)v.y, (bf16_t)v.z, (bf16_t)v.w };
        *(bf16x4*)&sA[wave][(s*64 + q*16 + r)*8 + j] = pk;
    }
    __syncthreads();
    int m = lane & 15, g = lane >> 4;
    bf16x8 aF[4];
#pragma unroll
    for (int s = 0; s < 4; ++s) aF[s] = *(const bf16x8*)&sA[wave][(s*64 + lane)*8];
#pragma unroll
    for (int t = 0; t < 8; ++t) {
        floatx4 a = {0.f,0.f,0.f,0.f};
#pragma unroll
        for (int s = 0; s < 4; ++s) {
            bf16x8 bF = *(const bf16x8*)&swW[((t*4+s)*64 + lane)*8];
            a = __builtin_amdgcn_mfma_f32_16x16x32_bf16(aF[s], bF, a, 0, 0, 0);
        }
#pragma unroll
        for (int rr = 0; rr < 4; ++rr) {
            int row = tb + g*4 + rr;
            if (row < Nt) tf[(size_t)row*128 + t*16 + m] = a[rr];
        }
    }
}

// ---------------------------------------------------------------------------
// K2: per-edge MLP + scatter-add. Both B matrices streamed from L2.
// LDS = 32 KB/block -> 5 blocks/CU (VGPR ~88 -> also 5 waves/SIMD).
// ---------------------------------------------------------------------------
__global__ __launch_bounds__(256) void k_edge(
    const float* __restrict__ cfeat, const float* __restrict__ cpose,
    const float* __restrict__ tpose, const int* __restrict__ hi,
    const int* __restrict__ wi, const float* __restrict__ W_rp,
    const float* __restrict__ b_rp, const float* __restrict__ g_ctx,
    const float* __restrict__ be_ctx, const bf16_t* __restrict__ swC1,
    const bf16_t* __restrict__ swC2, float* __restrict__ tf, int E)
{
    __shared__ alignas(16) bf16_t sA[4][4096];    // per-wave [16 x 256] A-frag order
    int tid = threadIdx.x, lane = tid & 63, wave = tid >> 6;

    int tb = (blockIdx.x * 4 + wave) * 16;
    int r = lane >> 2, cb = (lane & 3) * 32;
    int e = min(tb + r, E - 1);
    int ci = hi[e], ti = wi[e];
    // context features -> k in [0,128)
    const float4* src = (const float4*)(cfeat + (size_t)ci * 128 + cb);
#pragma unroll
    for (int i = 0; i < 8; ++i) {
        float4 v = src[i];
        int k = cb + 4*i;
        int s = k >> 5, q = (k >> 3) & 3, j = k & 7;
        bf16x4 pk = { (bf16_t)v.x, (bf16_t)v.y, (bf16_t)v.z, (bf16_t)v.w };
        *(bf16x4*)&sA[wave][(s*64 + q*16 + r)*8 + j] = pk;
    }
    // relpose MLP -> k in [128,256)
    float4 cp = ((const float4*)cpose)[ci];
    float4 tp = ((const float4*)tpose)[ti];
    float d0 = cp.x - tp.x, d1 = cp.y - tp.y, d2 = cp.z - tp.z, d3 = cp.w - tp.w;
#pragma unroll
    for (int i = 0; i < 8; ++i) {
        int c = cb + 4*i;
        float4 w0 = *(const float4*)(W_rp + c);
        float4 w1 = *(const float4*)(W_rp + 128 + c);
        float4 w2 = *(const float4*)(W_rp + 256 + c);
        float4 w3 = *(const float4*)(W_rp + 384 + c);
        float4 bb = *(const float4*)(b_rp + c);
        float o0 = fmaxf(d0*w0.x + d1*w1.x + d2*w2.x + d3*w3.x + bb.x, 0.f);
        float o1 = fmaxf(d0*w0.y + d1*w1.y + d2*w2.y + d3*w3.y + bb.y, 0.f);
        float o2 = fmaxf(d0*w0.z + d1*w1.z + d2*w2.z + d3*w3.z + bb.z, 0.f);
        float o3 = fmaxf(d0*w0.w + d1*w1.w + d2*w2.w + d3*w3.w + bb.w, 0.f);
        int k = 128 + c;
        int s = k >> 5, q = (k >> 3) & 3, j = k & 7;
        bf16x4 pk = { (bf16_t)o0, (bf16_t)o1, (bf16_t)o2, (bf16_t)o3 };
        *(bf16x4*)&sA[wave][(s*64 + q*16 + r)*8 + j] = pk;
    }
    __syncthreads();

    int m = lane & 15, g = lane >> 4;
    bf16x8 aF[8];
#pragma unroll
    for (int s = 0; s < 8; ++s) aF[s] = *(const bf16x8*)&sA[wave][(s*64 + lane)*8];
    floatx4 acc[8];
#pragma unroll
    for (int t = 0; t < 8; ++t) {
        floatx4 a = {0.f,0.f,0.f,0.f};
#pragma unroll
        for (int s = 0; s < 8; ++s) {
            bf16x8 bF = *(const bf16x8*)&swC1[(size_t)((t*8+s)*64 + lane)*8];
            a = __builtin_amdgcn_mfma_f32_16x16x32_bf16(aF[s], bF, a, 0, 0, 0);
        }
        acc[t] = a;
    }
    gn_rows(acc, lane, g_ctx, be_ctx, true);
    __syncthreads();
    // write h back into sA (A-frag order, K=128 region)
#pragma unroll
    for (int t = 0; t < 8; ++t) {
        int n = t*16 + m;
        int s = n >> 5, q = (n >> 3) & 3, j = n & 7;
#pragma unroll
        for (int rr = 0; rr < 4; ++rr)
            sA[wave][(s*64 + q*16 + (g*4+rr))*8 + j] = (bf16_t)acc[t][rr];
    }
    __syncthreads();
    bf16x8 aF2[4];
#pragma unroll
    for (int s = 0; s < 4; ++s) aF2[s] = *(const bf16x8*)&sA[wave][(s*64 + lane)*8];
    int dstrow[4]; bool vald[4];
#pragma unroll
    for (int rr = 0; rr < 4; ++rr) {
        int ee = tb + g*4 + rr;
        vald[rr] = ee < E;
        dstrow[rr] = vald[rr] ? wi[ee] : 0;
    }
#pragma unroll
    for (int t = 0; t < 8; ++t) {
        floatx4 a = {0.f,0.f,0.f,0.f};
#pragma unroll
        for (int s = 0; s < 4; ++s) {
            bf16x8 bF = *(const bf16x8*)&swC2[((t*4+s)*64 + lane)*8];
            a = __builtin_amdgcn_mfma_f32_16x16x32_bf16(aF2[s], bF, a, 0, 0, 0);
        }
#pragma unroll
        for (int rr = 0; rr < 4; ++rr) {
            if (vald[rr])
                atomicAdd(&tf[(size_t)dstrow[rr]*128 + t*16 + m], a[rr]);
        }
    }
}

// ---------------------------------------------------------------------------
// K3: out = relu(GN(relu(GN(relu(GN(tf)) @ W_m1)) @ W_m2) + identity)
// B matrices streamed from L2. LDS = 16 KB/block.
// ---------------------------------------------------------------------------
__global__ __launch_bounds__(256) void k_out(
    const float* __restrict__ tf, const float* __restrict__ identity,
    const float* __restrict__ g_n, const float* __restrict__ be_n,
    const float* __restrict__ g_m1, const float* __restrict__ be_m1,
    const float* __restrict__ g_m2, const float* __restrict__ be_m2,
    const bf16_t* __restrict__ swM1, const bf16_t* __restrict__ swM2,
    float* __restrict__ out, int Nt)
{
    __shared__ alignas(16) bf16_t sA[4][2048];
    int tid = threadIdx.x, lane = tid & 63, wave = tid >> 6;

    int tb = (blockIdx.x*4 + wave)*16;
    int r = lane >> 2, cb = (lane & 3)*32;
    int grow = tb + r;
    bool rv = grow < Nt;
    const float4* src = (const float4*)(tf + (size_t)(rv ? grow : 0)*128 + cb);
    float vals[32];
    float ls = 0.f, lq = 0.f;
#pragma unroll
    for (int i = 0; i < 8; ++i) {
        float4 v = rv ? src[i] : make_float4(0.f,0.f,0.f,0.f);
        vals[4*i+0]=v.x; vals[4*i+1]=v.y; vals[4*i+2]=v.z; vals[4*i+3]=v.w;
        ls += v.x+v.y+v.z+v.w;
        lq += v.x*v.x+v.y*v.y+v.z*v.z+v.w*v.w;
    }
    ls += __shfl_xor(ls,1); lq += __shfl_xor(lq,1);
    ls += __shfl_xor(ls,2); lq += __shfl_xor(lq,2);
    float mean = ls*(1.f/128.f);
    float inv = rsqrtf(lq*(1.f/128.f) - mean*mean + EPSF);
#pragma unroll
    for (int i = 0; i < 8; ++i) {
        int c = cb + 4*i;
        float4 ga = *(const float4*)(g_n + c);
        float4 be = *(const float4*)(be_n + c);
        float o0 = fmaxf((vals[4*i+0]-mean)*inv*ga.x + be.x, 0.f);
        float o1 = fmaxf((vals[4*i+1]-mean)*inv*ga.y + be.y, 0.f);
        float o2 = fmaxf((vals[4*i+2]-mean)*inv*ga.z + be.z, 0.f);
        float o3 = fmaxf((vals[4*i+3]-mean)*inv*ga.w + be.w, 0.f);
        int s = c >> 5, q = (c >> 3) & 3, j = c & 7;
        bf16x4 pk = { (bf16_t)o0, (bf16_t)o1, (bf16_t)o2, (bf16_t)o3 };
        *(bf16x4*)&sA[wave][(s*64 + q*16 + r)*8 + j] = pk;
    }
    __syncthreads();
    int m = lane & 15, g = lane >> 4;
    bf16x8 aF[4];
#pragma unroll
    for (int s = 0; s < 4; ++s) aF[s] = *(const bf16x8*)&sA[wave][(s*64 + lane)*8];
    floatx4 acc[8];
#pragma unroll
    for (int t = 0; t < 8; ++t) {
        floatx4 a = {0.f,0.f,0.f,0.f};
#pragma unroll
        for (int s = 0; s < 4; ++s) {
            bf16x8 bF = *(const bf16x8*)&swM1[((t*4+s)*64 + lane)*8];
            a = __builtin_amdgcn_mfma_f32_16x16x32_bf16(aF[s], bF, a, 0, 0, 0);
        }
        acc[t] = a;
    }
    gn_rows(acc, lane, g_m1, be_m1, true);
    __syncthreads();
#pragma unroll
    for (int t = 0; t < 8; ++t) {
        int n = t*16 + m;
        int s = n >> 5, q = (n >> 3) & 3, j = n & 7;
#pragma unroll
        for (int rr = 0; rr < 4; ++rr)
            sA[wave][(s*64 + q*16 + (g*4+rr))*8 + j] = (bf16_t)acc[t][rr];
    }
    __syncthreads();
#pragma unroll
    for (int s = 0; s < 4; ++s) aF[s] = *(const bf16x8*)&sA[wave][(s*64 + lane)*8];
#pragma unroll
    for (int t = 0; t < 8; ++t) {
        floatx4 a = {0.f,0.f,0.f,0.f};
#pragma unroll
        for (int s = 0; s < 4; ++s) {
            bf16x8 bF = *(const bf16x8*)&swM2[((t*4+s)*64 + lane)*8];
            a = __builtin_amdgcn_mfma_f32_16x16x32_bf16(aF[s], bF, a, 0, 0, 0);
        }
        acc[t] = a;
    }
    gn_rows(acc, lane, g_m2, be_m2, false);
#pragma unroll
    for (int t = 0; t < 8; ++t) {
        int n = t*16 + m;
#pragma unroll
        for (int rr = 0; rr < 4; ++rr) {
            int row = tb + g*4 + rr;
            if (row < Nt) {
                float v = acc[t][rr] + identity[(size_t)row*128 + n];
                out[(size_t)row*128 + n] = fmaxf(v, 0.f);
            }
        }
    }
}

// ---------------------------------------------------------------------------
extern "C" void kernel_launch(void* const* d_in, const int* in_sizes, int n_in,
                              void* d_out, int out_size, void* d_ws, size_t ws_size,
                              hipStream_t stream)
{
    const float* cfeat  = (const float*)d_in[0];
    const float* tfeat  = (const float*)d_in[1];
    const float* cpose  = (const float*)d_in[2];
    const float* tpose  = (const float*)d_in[3];
    const int*   hi     = (const int*)d_in[4];
    const int*   wi     = (const int*)d_in[5];
    const float* W_in   = (const float*)d_in[6];
    const float* W_rp   = (const float*)d_in[7];
    const float* b_rp   = (const float*)d_in[8];
    const float* W_ctx1 = (const float*)d_in[9];
    const float* g_ctx  = (const float*)d_in[10];
    const float* be_ctx = (const float*)d_in[11];
    const float* W_ctx2 = (const float*)d_in[12];
    const float* g_n    = (const float*)d_in[13];
    const float* be_n   = (const float*)d_in[14];
    const float* W_m1   = (const float*)d_in[15];
    const float* g_m1   = (const float*)d_in[16];
    const float* be_m1  = (const float*)d_in[17];
    const float* W_m2   = (const float*)d_in[18];
    const float* g_m2   = (const float*)d_in[19];
    const float* be_m2  = (const float*)d_in[20];

    int Nt = in_sizes[1] / 128;
    int E  = in_sizes[4];
    float* outp = (float*)d_out;

    float*  tf = (float*)d_ws;                                   // [Nt,128] f32
    bf16_t* sw = (bf16_t*)((char*)d_ws + (size_t)Nt * 128 * sizeof(float));
    bf16_t* swIn = sw;
    bf16_t* swC1 = sw + 16384;
    bf16_t* swC2 = sw + 49152;
    bf16_t* swM1 = sw + 65536;
    bf16_t* swM2 = sw + 81920;

    k_prep<<<384, 256, 0, stream>>>(W_in, W_ctx1, W_ctx2, W_m1, W_m2, sw);
    k_gemm_in<<<(Nt + 63) / 64, 256, 0, stream>>>(tfeat, swIn, tf, Nt);
    k_edge<<<(E + 63) / 64, 256, 0, stream>>>(cfeat, cpose, tpose, hi, wi,
                                              W_rp, b_rp, g_ctx, be_ctx,
                                              swC1, swC2, tf, E);
    k_out<<<(Nt + 63) / 64, 256, 0, stream>>>(tf, tfeat, g_n, be_n, g_m1, be_m1,
                                              g_m2, be_m2, swM1, swM2, outp, Nt);
}